// Round 7
// baseline (10857.060 us; speedup 1.0000x reference)
//
#include <hip/hip_runtime.h>

typedef __attribute__((ext_vector_type(8))) short          short8;  // bf16x8 MFMA frag (4 VGPR)
typedef __attribute__((ext_vector_type(4))) float          f32x4;   // MFMA accumulator
typedef __attribute__((ext_vector_type(8))) unsigned short us8;

#define BTOT 65536
#define TT   30

// ---- frag-major layout: X[R][K] stored as [R/16][K/8][16][8] shorts ----
// addr(r,k) = (r>>4)*(K*16) + (k>>3)*128 + (r&15)*8 + (k&7)
// A wave's 16x16x32-MFMA fragment is 1024 CONTIGUOUS bytes.

static __device__ __forceinline__ unsigned short f2bf(float f) {
    unsigned u = __float_as_uint(f);
    u = (u + 0x7FFFu + ((u >> 16) & 1u)) >> 16;   // RNE; finite values only
    return (unsigned short)u;
}
static __device__ __forceinline__ float bf2f(unsigned short h) {
    return __uint_as_float(((unsigned)h) << 16);
}

__device__ __forceinline__ float fast_tanh(float v) {
    float e = __builtin_amdgcn_exp2f(v * 2.885390081777927f);
    float r = __builtin_amdgcn_rcpf(e + 1.0f);
    return fmaf(-2.0f, r, 1.0f);
}

// ---------------- weight splitter: fp32 [M][K] -> frag-major bf16 hi/mid/lo ----------------
__global__ void split_kernel(const float* __restrict__ src, unsigned short* __restrict__ dh,
                             unsigned short* __restrict__ dm, unsigned short* __restrict__ dl,
                             int n, int K) {
    int i = blockIdx.x * 256 + threadIdx.x;
    if (i < n) {
        int m = i / K, k = i % K;
        float v = src[i];
        unsigned short a = f2bf(v); float r1 = v - bf2f(a);
        unsigned short b = f2bf(r1);
        unsigned short c = f2bf(r1 - bf2f(b));
        size_t o = (size_t)(m >> 4) * (K * 16) + (size_t)(k >> 3) * 128 + (m & 15) * 8 + (k & 7);
        dh[o] = a; dm[o] = b; dl[o] = c;
    }
}

// ---------------- RNN: fused 5 layers, 1 thread = 1 sample; LDS weights; frag-major epilogue ----------------
__global__ __launch_bounds__(256, 1) void rnn_kernel(
    const float* __restrict__ x, const float* __restrict__ h0,
    const float* __restrict__ Wih0, const float* __restrict__ WihR,
    const float* __restrict__ Whh, const float* __restrict__ bih,
    const float* __restrict__ bhh,
    unsigned short* __restrict__ Yh, unsigned short* __restrict__ Ym,
    unsigned short* __restrict__ Yl, int base, int Bs)
{
    // weights resident in LDS: broadcast ds_reads replace per-timestep s_load streams
    __shared__ float sWih0[96];          // [32][3]
    __shared__ float sWihR[4096];        // [4][32][32]
    __shared__ float sWhh[5120];         // [5][32][32]
    __shared__ float sB[160];            // [5][32]  (bih+bhh)

    const int tid = threadIdx.x;
    for (int i = tid; i < 96; i += 256)   sWih0[i] = Wih0[i];
    for (int i = tid; i < 4096; i += 256) sWihR[i] = WihR[i];
    for (int i = tid; i < 5120; i += 256) sWhh[i]  = Whh[i];
    for (int i = tid; i < 160; i += 256)  sB[i]    = bih[i] + bhh[i];
    __syncthreads();

    const int bl = blockIdx.x * 256 + tid;
    const int b  = base + bl;
    float h[5][32];
#pragma unroll
    for (int l = 0; l < 5; ++l)
#pragma unroll
        for (int j = 0; j < 32; ++j)
            h[l][j] = h0[((size_t)l * BTOT + b) * 32 + j];

    const float* xb = x + (size_t)b * (TT * 3);
    const size_t rowb = (size_t)(bl >> 4) * (960 * 16) + (bl & 15) * 8;

#pragma unroll 1
    for (int t = 0; t < TT; ++t) {
        const float in0 = xb[t * 3 + 0];
        const float in1 = xb[t * 3 + 1];
        const float in2 = xb[t * 3 + 2];
        float y[32];
#pragma unroll
        for (int j = 0; j < 32; ++j) {
            float a = sB[j];
            a = fmaf(sWih0[j * 3 + 0], in0, a);
            a = fmaf(sWih0[j * 3 + 1], in1, a);
            a = fmaf(sWih0[j * 3 + 2], in2, a);
#pragma unroll
            for (int k = 0; k < 32; ++k)
                a = fmaf(sWhh[j * 32 + k], h[0][k], a);
            y[j] = fast_tanh(a);
        }
#pragma unroll
        for (int j = 0; j < 32; ++j) h[0][j] = y[j];
#pragma unroll
        for (int l = 1; l < 5; ++l) {
#pragma unroll
            for (int j = 0; j < 32; ++j) {
                float a = sB[l * 32 + j];
#pragma unroll
                for (int k = 0; k < 32; ++k)
                    a = fmaf(sWihR[((l - 1) * 32 + j) * 32 + k], h[l - 1][k], a);
#pragma unroll
                for (int k = 0; k < 32; ++k)
                    a = fmaf(sWhh[(l * 32 + j) * 32 + k], h[l][k], a);
                y[j] = fast_tanh(a);
            }
#pragma unroll
            for (int j = 0; j < 32; ++j) h[l][j] = y[j];
        }
        // split-bf16 store to frag-major layout (row-length 960): 16B stores, coalesced
        us8 th, tm, tl;
#pragma unroll
        for (int j = 0; j < 32; ++j) {
            float v = h[4][j];
            unsigned short a = f2bf(v); float r1 = v - bf2f(a);
            unsigned short m = f2bf(r1);
            unsigned short c = f2bf(r1 - bf2f(m));
            th[j & 7] = a; tm[j & 7] = m; tl[j & 7] = c;
            if ((j & 7) == 7) {
                const size_t o = rowb + (size_t)(t * 4 + (j >> 3)) * 128;
                *(us8*)(Yh + o) = th; *(us8*)(Ym + o) = tm; *(us8*)(Yl + o) = tl;
            }
        }
    }
}

// ---------------- FC via MFMA, 3-way split-bf16 (6 products), frag-major I/O ----------------
template <int M, int K, int FW, int SW, int RELU>
__global__ __launch_bounds__(512, 2) void fcm_kernel(
    const unsigned short* __restrict__ Wh, const unsigned short* __restrict__ Wm,
    const unsigned short* __restrict__ Wl, const float* __restrict__ bias,
    const unsigned short* __restrict__ Ih, const unsigned short* __restrict__ Im,
    const unsigned short* __restrict__ Il,
    unsigned short* __restrict__ Oh, unsigned short* __restrict__ Om,
    unsigned short* __restrict__ Ol)
{
    const int lane = threadIdx.x & 63;
    const int wv   = threadIdx.x >> 6;           // 0..7
    const int fq   = wv % FW;
    const int sq   = wv / FW;
    const int sb   = blockIdx.x * (SW * 64) + sq * 64;   // 64-aligned
    const int fb   = fq * 64;
    const int lr   = lane & 15;
    const int lg   = lane >> 4;

    f32x4 acc[4][4] = {};

    const size_t aBase = (size_t)(sb >> 4) * (K * 16) + (size_t)lg * 128 + lr * 8;
    const size_t bBase = (size_t)(fb >> 4) * (K * 16) + (size_t)lg * 128 + lr * 8;

#pragma unroll 1
    for (int kc = 0; kc < K; kc += 32) {
        const size_t ko = (size_t)kc * 16;
        short8 a0[4], a1[4], a2[4];
#pragma unroll
        for (int st = 0; st < 4; ++st) {
            const size_t o = aBase + (size_t)st * (K * 16) + ko;
            a0[st] = *(const short8*)(Ih + o);
            a1[st] = *(const short8*)(Im + o);
            a2[st] = *(const short8*)(Il + o);
        }
#pragma unroll
        for (int ft = 0; ft < 4; ++ft) {
            const size_t o = bBase + (size_t)ft * (K * 16) + ko;
            const short8 b0 = *(const short8*)(Wh + o);
            const short8 b1 = *(const short8*)(Wm + o);
            const short8 b2 = *(const short8*)(Wl + o);
#pragma unroll
            for (int st = 0; st < 4; ++st) {
                f32x4 c = acc[st][ft];
                c = __builtin_amdgcn_mfma_f32_16x16x32_bf16(a0[st], b0, c, 0, 0, 0);
                c = __builtin_amdgcn_mfma_f32_16x16x32_bf16(a0[st], b1, c, 0, 0, 0);
                c = __builtin_amdgcn_mfma_f32_16x16x32_bf16(a1[st], b0, c, 0, 0, 0);
                c = __builtin_amdgcn_mfma_f32_16x16x32_bf16(a0[st], b2, c, 0, 0, 0);
                c = __builtin_amdgcn_mfma_f32_16x16x32_bf16(a2[st], b0, c, 0, 0, 0);
                c = __builtin_amdgcn_mfma_f32_16x16x32_bf16(a1[st], b1, c, 0, 0, 0);
                acc[st][ft] = c;
            }
        }
    }

#pragma unroll
    for (int st = 0; st < 4; ++st)
#pragma unroll
        for (int ft = 0; ft < 4; ++ft) {
            const int feat = fb + ft * 16 + lr;
            const float bv = bias[feat];
#pragma unroll
            for (int r = 0; r < 4; ++r) {
                const int smp = sb + st * 16 + lg * 4 + r;
                float v = acc[st][ft][r] + bv;
                if (RELU) v = fmaxf(v, 0.0f);
                unsigned short hh = f2bf(v);  float r1 = v - bf2f(hh);
                unsigned short mm = f2bf(r1);
                unsigned short ll = f2bf(r1 - bf2f(mm));
                // frag-major store, row-length M (this is the next layer's K)
                const size_t o = (size_t)(smp >> 4) * (M * 16) + (size_t)(feat >> 3) * 128
                               + (smp & 15) * 8 + (feat & 7);
                Oh[o] = hh; Om[o] = mm; Ol[o] = ll;
            }
        }
}

// ---------------- final dot: out[b] = W5 . (Ah+Am+Al)[b,:] + b5 (frag-major input, K=64) ----------------
__global__ __launch_bounds__(256) void fc5_kernel(
    const float* __restrict__ W5, const float* __restrict__ b5,
    const unsigned short* __restrict__ Ah, const unsigned short* __restrict__ Am,
    const unsigned short* __restrict__ Al, float* __restrict__ Out, int base)
{
    const int bl = blockIdx.x * 256 + threadIdx.x;
    const size_t rowb = (size_t)(bl >> 4) * (64 * 16) + (bl & 15) * 8;
    float acc = b5[0];
#pragma unroll
    for (int k8 = 0; k8 < 8; ++k8) {
        const size_t o = rowb + (size_t)k8 * 128;
        const us8 vh = *(const us8*)(Ah + o);
        const us8 vm = *(const us8*)(Am + o);
        const us8 vl = *(const us8*)(Al + o);
#pragma unroll
        for (int j = 0; j < 8; ++j) {
            float v = bf2f(vh[j]) + bf2f(vm[j]) + bf2f(vl[j]);
            acc = fmaf(v, W5[k8 * 8 + j], acc);
        }
    }
    Out[base + bl] = acc;
}

extern "C" void kernel_launch(void* const* d_in, const int* in_sizes, int n_in,
                              void* d_out, int out_size, void* d_ws, size_t ws_size,
                              hipStream_t stream)
{
    const float* x    = (const float*)d_in[0];
    const float* h0   = (const float*)d_in[1];
    const float* Wih0 = (const float*)d_in[2];
    const float* WihR = (const float*)d_in[3];
    const float* Whh  = (const float*)d_in[4];
    const float* bih  = (const float*)d_in[5];
    const float* bhh  = (const float*)d_in[6];
    const float* W1 = (const float*)d_in[7];   const float* b1 = (const float*)d_in[8];
    const float* W2 = (const float*)d_in[9];   const float* b2 = (const float*)d_in[10];
    const float* W3 = (const float*)d_in[11];  const float* b3 = (const float*)d_in[12];
    const float* W4 = (const float*)d_in[13];  const float* b4 = (const float*)d_in[14];
    const float* W5 = (const float*)d_in[15];  const float* b5 = (const float*)d_in[16];
    float* out = (float*)d_out;

    // ---- bump allocator on d_ws ----
    size_t off = 0;
    auto alloc = [&](size_t bytes) -> void* {
        off = (off + 255) & ~(size_t)255;
        void* p = (char*)d_ws + off;
        off += bytes;
        return p;
    };
    const int nW1 = 512 * 960, nW2 = 256 * 512, nW3 = 128 * 256, nW4 = 64 * 128;
    unsigned short *W1h = (unsigned short*)alloc((size_t)nW1 * 2), *W1m = (unsigned short*)alloc((size_t)nW1 * 2), *W1l = (unsigned short*)alloc((size_t)nW1 * 2);
    unsigned short *W2h = (unsigned short*)alloc((size_t)nW2 * 2), *W2m = (unsigned short*)alloc((size_t)nW2 * 2), *W2l = (unsigned short*)alloc((size_t)nW2 * 2);
    unsigned short *W3h = (unsigned short*)alloc((size_t)nW3 * 2), *W3m = (unsigned short*)alloc((size_t)nW3 * 2), *W3l = (unsigned short*)alloc((size_t)nW3 * 2);
    unsigned short *W4h = (unsigned short*)alloc((size_t)nW4 * 2), *W4m = (unsigned short*)alloc((size_t)nW4 * 2), *W4l = (unsigned short*)alloc((size_t)nW4 * 2);
    const size_t fixed = off + 4096;

    size_t Bc = BTOT;
    while (Bc > 1024 && fixed + (size_t)8832 * Bc > ws_size) Bc >>= 1;
    const int Bs = (int)Bc;

    unsigned short *Yh = (unsigned short*)alloc(Bc * 960 * 2), *Ym = (unsigned short*)alloc(Bc * 960 * 2), *Yl = (unsigned short*)alloc(Bc * 960 * 2);
    unsigned short *A1h = (unsigned short*)alloc(Bc * 512 * 2), *A1m = (unsigned short*)alloc(Bc * 512 * 2), *A1l = (unsigned short*)alloc(Bc * 512 * 2);
    unsigned short *A2h = Yh,  *A2m = Ym,  *A2l = Yl;    // overlays (dead regions)
    unsigned short *A3h = A1h, *A3m = A1m, *A3l = A1l;
    unsigned short *A4h = Yh,  *A4m = Ym,  *A4l = Yl;

    split_kernel<<<(nW1 + 255) / 256, 256, 0, stream>>>(W1, W1h, W1m, W1l, nW1, 960);
    split_kernel<<<(nW2 + 255) / 256, 256, 0, stream>>>(W2, W2h, W2m, W2l, nW2, 512);
    split_kernel<<<(nW3 + 255) / 256, 256, 0, stream>>>(W3, W3h, W3m, W3l, nW3, 256);
    split_kernel<<<(nW4 + 255) / 256, 256, 0, stream>>>(W4, W4h, W4m, W4l, nW4, 128);

    for (size_t base = 0; base < BTOT; base += Bc) {
        rnn_kernel<<<Bs / 256, 256, 0, stream>>>(x, h0, Wih0, WihR, Whh, bih, bhh,
                                                 Yh, Ym, Yl, (int)base, Bs);
        fcm_kernel<512, 960, 8, 1, 1><<<Bs / 64, 512, 0, stream>>>(
            W1h, W1m, W1l, b1, Yh, Ym, Yl, A1h, A1m, A1l);
        fcm_kernel<256, 512, 4, 2, 1><<<Bs / 128, 512, 0, stream>>>(
            W2h, W2m, W2l, b2, A1h, A1m, A1l, A2h, A2m, A2l);
        fcm_kernel<128, 256, 2, 4, 1><<<Bs / 256, 512, 0, stream>>>(
            W3h, W3m, W3l, b3, A2h, A2m, A2l, A3h, A3m, A3l);
        fcm_kernel<64, 128, 1, 8, 1><<<Bs / 512, 512, 0, stream>>>(
            W4h, W4m, W4l, b4, A3h, A3m, A3l, A4h, A4m, A4l);
        fc5_kernel<<<Bs / 256, 256, 0, stream>>>(W5, b5, A4h, A4m, A4l, out, (int)base);
    }
}

// Round 14
// 3020.079 us; speedup vs baseline: 3.5950x; 3.5950x over previous
//
#include <hip/hip_runtime.h>

typedef __attribute__((ext_vector_type(8))) short          short8;  // bf16x8 MFMA frag (4 VGPR)
typedef __attribute__((ext_vector_type(4))) float          f32x4;   // MFMA accumulator
typedef __attribute__((ext_vector_type(8))) unsigned short us8;

#define BTOT 65536
#define TT   30

// ---- frag-major layout: X[R][K] stored as [R/16][K/8][16][8] shorts ----
// addr(r,k) = (r>>4)*(K*16) + (k>>3)*128 + (r&15)*8 + (k&7)

static __device__ __forceinline__ unsigned short f2bf(float f) {
    unsigned u = __float_as_uint(f);
    u = (u + 0x7FFFu + ((u >> 16) & 1u)) >> 16;   // RNE; finite values only
    return (unsigned short)u;
}
static __device__ __forceinline__ float bf2f(unsigned short h) {
    return __uint_as_float(((unsigned)h) << 16);
}

__device__ __forceinline__ float fast_tanh(float v) {
    float e = __builtin_amdgcn_exp2f(v * 2.885390081777927f);
    float r = __builtin_amdgcn_rcpf(e + 1.0f);
    return fmaf(-2.0f, r, 1.0f);
}

// ---------------- weight splitter: fp32 [M][K] -> frag-major bf16 hi/mid/lo ----------------
__global__ void split_kernel(const float* __restrict__ src, unsigned short* __restrict__ dh,
                             unsigned short* __restrict__ dm, unsigned short* __restrict__ dl,
                             int n, int K) {
    int i = blockIdx.x * 256 + threadIdx.x;
    if (i < n) {
        int m = i / K, k = i % K;
        float v = src[i];
        unsigned short a = f2bf(v); float r1 = v - bf2f(a);
        unsigned short b = f2bf(r1);
        unsigned short c = f2bf(r1 - bf2f(b));
        size_t o = (size_t)(m >> 4) * (K * 16) + (size_t)(k >> 3) * 128 + (m & 15) * 8 + (k & 7);
        dh[o] = a; dm[o] = b; dl[o] = c;
    }
}

// ---------------- RNN v3: 4-wave j-split, lane = sample, h-state in LDS, s_load weights ----------------
// Block: 256 threads = 4 waves x 64 samples. Wave wv owns outputs j in [8*wv, 8*wv+8).
// hS[l][k][s]: lane s reads/writes only column s; j-ranges exchanged across waves via barriers.
__global__ __launch_bounds__(256, 4) void rnn_kernel(
    const float* __restrict__ x, const float* __restrict__ h0,
    const float* __restrict__ Wih0, const float* __restrict__ WihR,
    const float* __restrict__ Whh, const float* __restrict__ bih,
    const float* __restrict__ bhh,
    unsigned short* __restrict__ Yh, unsigned short* __restrict__ Ym,
    unsigned short* __restrict__ Yl, int base, int Bs)
{
    __shared__ float hS[5][32][64];   // 40960 B

    const int tid  = threadIdx.x;
    const int wv   = __builtin_amdgcn_readfirstlane(tid >> 6);  // wave-uniform
    const int s    = tid & 63;                                   // lane = local sample
    const int j0   = wv * 8;
    const int bl   = blockIdx.x * 64 + s;    // chunk-local sample
    const int b    = base + bl;              // global sample

    // init h-state (one-time)
    for (int i = tid; i < 5 * 32 * 64; i += 256) {
        const int ss = i & 63, k = (i >> 6) & 31, l = i >> 11;
        hS[l][k][ss] = h0[((size_t)l * BTOT + base + blockIdx.x * 64 + ss) * 32 + k];
    }
    __syncthreads();

    const float* xb = x + (size_t)b * (TT * 3);
    const size_t rowb = (size_t)(bl >> 4) * (960 * 16) + (bl & 15) * 8;

    float y[8];
#pragma unroll 1
    for (int t = 0; t < TT; ++t) {
        // ---- layer 0 (input dim 3) ----
        const float in0 = xb[t * 3 + 0];
        const float in1 = xb[t * 3 + 1];
        const float in2 = xb[t * 3 + 2];
        {
            float hk[32];
#pragma unroll
            for (int k = 0; k < 32; ++k) hk[k] = hS[0][k][s];
#pragma unroll
            for (int j = 0; j < 8; ++j) {
                const int jj = j0 + j;
                float a = bih[jj] + bhh[jj];
                a = fmaf(Wih0[jj * 3 + 0], in0, a);
                a = fmaf(Wih0[jj * 3 + 1], in1, a);
                a = fmaf(Wih0[jj * 3 + 2], in2, a);
#pragma unroll
                for (int k = 0; k < 32; ++k)
                    a = fmaf(Whh[jj * 32 + k], hk[k], a);
                y[j] = fast_tanh(a);
            }
            __syncthreads();          // all waves done reading hS[0]
#pragma unroll
            for (int j = 0; j < 8; ++j) hS[0][j0 + j][s] = y[j];
            __syncthreads();          // writes visible
        }
        // ---- layers 1..4 ----
#pragma unroll 1
        for (int l = 1; l < 5; ++l) {
            float hp[32], hc[32];
#pragma unroll
            for (int k = 0; k < 32; ++k) { hp[k] = hS[l - 1][k][s]; hc[k] = hS[l][k][s]; }
#pragma unroll
            for (int j = 0; j < 8; ++j) {
                const int jj = j0 + j;
                float a = bih[l * 32 + jj] + bhh[l * 32 + jj];
#pragma unroll
                for (int k = 0; k < 32; ++k)
                    a = fmaf(WihR[((size_t)(l - 1) * 32 + jj) * 32 + k], hp[k], a);
#pragma unroll
                for (int k = 0; k < 32; ++k)
                    a = fmaf(Whh[((size_t)l * 32 + jj) * 32 + k], hc[k], a);
                y[j] = fast_tanh(a);
            }
            __syncthreads();          // all waves done reading hS[l-1], hS[l]
#pragma unroll
            for (int j = 0; j < 8; ++j) hS[l][j0 + j][s] = y[j];
            __syncthreads();
        }
        // ---- epilogue: y[] holds layer-4 outputs j0..j0+7; split-bf16 frag-major store ----
        // col = t*32 + j0 + j -> (col>>3) = t*4 + wv, col&7 = j  => one 16B store per array
        us8 th, tm, tl;
#pragma unroll
        for (int j = 0; j < 8; ++j) {
            const float v = y[j];
            const unsigned short a = f2bf(v); const float r1 = v - bf2f(a);
            const unsigned short m = f2bf(r1);
            const unsigned short c = f2bf(r1 - bf2f(m));
            th[j] = a; tm[j] = m; tl[j] = c;
        }
        const size_t o = rowb + (size_t)(t * 4 + wv) * 128;
        *(us8*)(Yh + o) = th; *(us8*)(Ym + o) = tm; *(us8*)(Yl + o) = tl;
    }
}

// ---------------- FC via MFMA, 3-way split-bf16 (6 products), frag-major I/O ----------------
template <int M, int K, int FW, int SW, int RELU>
__global__ __launch_bounds__(512, 2) void fcm_kernel(
    const unsigned short* __restrict__ Wh, const unsigned short* __restrict__ Wm,
    const unsigned short* __restrict__ Wl, const float* __restrict__ bias,
    const unsigned short* __restrict__ Ih, const unsigned short* __restrict__ Im,
    const unsigned short* __restrict__ Il,
    unsigned short* __restrict__ Oh, unsigned short* __restrict__ Om,
    unsigned short* __restrict__ Ol)
{
    const int lane = threadIdx.x & 63;
    const int wv   = threadIdx.x >> 6;           // 0..7
    const int fq   = wv % FW;
    const int sq   = wv / FW;
    const int sb   = blockIdx.x * (SW * 64) + sq * 64;   // 64-aligned
    const int fb   = fq * 64;
    const int lr   = lane & 15;
    const int lg   = lane >> 4;

    f32x4 acc[4][4] = {};

    const size_t aBase = (size_t)(sb >> 4) * (K * 16) + (size_t)lg * 128 + lr * 8;
    const size_t bBase = (size_t)(fb >> 4) * (K * 16) + (size_t)lg * 128 + lr * 8;

#pragma unroll 1
    for (int kc = 0; kc < K; kc += 32) {
        const size_t ko = (size_t)kc * 16;
        short8 a0[4], a1[4], a2[4];
#pragma unroll
        for (int st = 0; st < 4; ++st) {
            const size_t o = aBase + (size_t)st * (K * 16) + ko;
            a0[st] = *(const short8*)(Ih + o);
            a1[st] = *(const short8*)(Im + o);
            a2[st] = *(const short8*)(Il + o);
        }
#pragma unroll
        for (int ft = 0; ft < 4; ++ft) {
            const size_t o = bBase + (size_t)ft * (K * 16) + ko;
            const short8 b0 = *(const short8*)(Wh + o);
            const short8 b1 = *(const short8*)(Wm + o);
            const short8 b2 = *(const short8*)(Wl + o);
#pragma unroll
            for (int st = 0; st < 4; ++st) {
                f32x4 c = acc[st][ft];
                c = __builtin_amdgcn_mfma_f32_16x16x32_bf16(a0[st], b0, c, 0, 0, 0);
                c = __builtin_amdgcn_mfma_f32_16x16x32_bf16(a0[st], b1, c, 0, 0, 0);
                c = __builtin_amdgcn_mfma_f32_16x16x32_bf16(a1[st], b0, c, 0, 0, 0);
                c = __builtin_amdgcn_mfma_f32_16x16x32_bf16(a0[st], b2, c, 0, 0, 0);
                c = __builtin_amdgcn_mfma_f32_16x16x32_bf16(a2[st], b0, c, 0, 0, 0);
                c = __builtin_amdgcn_mfma_f32_16x16x32_bf16(a1[st], b1, c, 0, 0, 0);
                acc[st][ft] = c;
            }
        }
    }

#pragma unroll
    for (int st = 0; st < 4; ++st)
#pragma unroll
        for (int ft = 0; ft < 4; ++ft) {
            const int feat = fb + ft * 16 + lr;
            const float bv = bias[feat];
#pragma unroll
            for (int r = 0; r < 4; ++r) {
                const int smp = sb + st * 16 + lg * 4 + r;
                float v = acc[st][ft][r] + bv;
                if (RELU) v = fmaxf(v, 0.0f);
                unsigned short hh = f2bf(v);  float r1 = v - bf2f(hh);
                unsigned short mm = f2bf(r1);
                unsigned short ll = f2bf(r1 - bf2f(mm));
                const size_t o = (size_t)(smp >> 4) * (M * 16) + (size_t)(feat >> 3) * 128
                               + (smp & 15) * 8 + (feat & 7);
                Oh[o] = hh; Om[o] = mm; Ol[o] = ll;
            }
        }
}

// ---------------- final dot: out[b] = W5 . (Ah+Am+Al)[b,:] + b5 (frag-major input, K=64) ----------------
__global__ __launch_bounds__(256) void fc5_kernel(
    const float* __restrict__ W5, const float* __restrict__ b5,
    const unsigned short* __restrict__ Ah, const unsigned short* __restrict__ Am,
    const unsigned short* __restrict__ Al, float* __restrict__ Out, int base)
{
    const int bl = blockIdx.x * 256 + threadIdx.x;
    const size_t rowb = (size_t)(bl >> 4) * (64 * 16) + (bl & 15) * 8;
    float acc = b5[0];
#pragma unroll
    for (int k8 = 0; k8 < 8; ++k8) {
        const size_t o = rowb + (size_t)k8 * 128;
        const us8 vh = *(const us8*)(Ah + o);
        const us8 vm = *(const us8*)(Am + o);
        const us8 vl = *(const us8*)(Al + o);
#pragma unroll
        for (int j = 0; j < 8; ++j) {
            float v = bf2f(vh[j]) + bf2f(vm[j]) + bf2f(vl[j]);
            acc = fmaf(v, W5[k8 * 8 + j], acc);
        }
    }
    Out[base + bl] = acc;
}

extern "C" void kernel_launch(void* const* d_in, const int* in_sizes, int n_in,
                              void* d_out, int out_size, void* d_ws, size_t ws_size,
                              hipStream_t stream)
{
    const float* x    = (const float*)d_in[0];
    const float* h0   = (const float*)d_in[1];
    const float* Wih0 = (const float*)d_in[2];
    const float* WihR = (const float*)d_in[3];
    const float* Whh  = (const float*)d_in[4];
    const float* bih  = (const float*)d_in[5];
    const float* bhh  = (const float*)d_in[6];
    const float* W1 = (const float*)d_in[7];   const float* b1 = (const float*)d_in[8];
    const float* W2 = (const float*)d_in[9];   const float* b2 = (const float*)d_in[10];
    const float* W3 = (const float*)d_in[11];  const float* b3 = (const float*)d_in[12];
    const float* W4 = (const float*)d_in[13];  const float* b4 = (const float*)d_in[14];
    const float* W5 = (const float*)d_in[15];  const float* b5 = (const float*)d_in[16];
    float* out = (float*)d_out;

    // ---- bump allocator on d_ws ----
    size_t off = 0;
    auto alloc = [&](size_t bytes) -> void* {
        off = (off + 255) & ~(size_t)255;
        void* p = (char*)d_ws + off;
        off += bytes;
        return p;
    };
    const int nW1 = 512 * 960, nW2 = 256 * 512, nW3 = 128 * 256, nW4 = 64 * 128;
    unsigned short *W1h = (unsigned short*)alloc((size_t)nW1 * 2), *W1m = (unsigned short*)alloc((size_t)nW1 * 2), *W1l = (unsigned short*)alloc((size_t)nW1 * 2);
    unsigned short *W2h = (unsigned short*)alloc((size_t)nW2 * 2), *W2m = (unsigned short*)alloc((size_t)nW2 * 2), *W2l = (unsigned short*)alloc((size_t)nW2 * 2);
    unsigned short *W3h = (unsigned short*)alloc((size_t)nW3 * 2), *W3m = (unsigned short*)alloc((size_t)nW3 * 2), *W3l = (unsigned short*)alloc((size_t)nW3 * 2);
    unsigned short *W4h = (unsigned short*)alloc((size_t)nW4 * 2), *W4m = (unsigned short*)alloc((size_t)nW4 * 2), *W4l = (unsigned short*)alloc((size_t)nW4 * 2);
    const size_t fixed = off + 4096;

    size_t Bc = BTOT;
    while (Bc > 1024 && fixed + (size_t)8832 * Bc > ws_size) Bc >>= 1;
    const int Bs = (int)Bc;

    unsigned short *Yh = (unsigned short*)alloc(Bc * 960 * 2), *Ym = (unsigned short*)alloc(Bc * 960 * 2), *Yl = (unsigned short*)alloc(Bc * 960 * 2);
    unsigned short *A1h = (unsigned short*)alloc(Bc * 512 * 2), *A1m = (unsigned short*)alloc(Bc * 512 * 2), *A1l = (unsigned short*)alloc(Bc * 512 * 2);
    unsigned short *A2h = Yh,  *A2m = Ym,  *A2l = Yl;    // overlays (dead regions)
    unsigned short *A3h = A1h, *A3m = A1m, *A3l = A1l;
    unsigned short *A4h = Yh,  *A4m = Ym,  *A4l = Yl;

    split_kernel<<<(nW1 + 255) / 256, 256, 0, stream>>>(W1, W1h, W1m, W1l, nW1, 960);
    split_kernel<<<(nW2 + 255) / 256, 256, 0, stream>>>(W2, W2h, W2m, W2l, nW2, 512);
    split_kernel<<<(nW3 + 255) / 256, 256, 0, stream>>>(W3, W3h, W3m, W3l, nW3, 256);
    split_kernel<<<(nW4 + 255) / 256, 256, 0, stream>>>(W4, W4h, W4m, W4l, nW4, 128);

    for (size_t base = 0; base < BTOT; base += Bc) {
        rnn_kernel<<<Bs / 64, 256, 0, stream>>>(x, h0, Wih0, WihR, Whh, bih, bhh,
                                                Yh, Ym, Yl, (int)base, Bs);
        fcm_kernel<512, 960, 8, 1, 1><<<Bs / 64, 512, 0, stream>>>(
            W1h, W1m, W1l, b1, Yh, Ym, Yl, A1h, A1m, A1l);
        fcm_kernel<256, 512, 4, 2, 1><<<Bs / 128, 512, 0, stream>>>(
            W2h, W2m, W2l, b2, A1h, A1m, A1l, A2h, A2m, A2l);
        fcm_kernel<128, 256, 2, 4, 1><<<Bs / 256, 512, 0, stream>>>(
            W3h, W3m, W3l, b3, A2h, A2m, A2l, A3h, A3m, A3l);
        fcm_kernel<64, 128, 1, 8, 1><<<Bs / 512, 512, 0, stream>>>(
            W4h, W4m, W4l, b4, A3h, A3m, A3l, A4h, A4m, A4l);
        fc5_kernel<<<Bs / 256, 256, 0, stream>>>(W5, b5, A4h, A4m, A4l, out, (int)base);
    }
}